// Round 1
// baseline (874.299 us; speedup 1.0000x reference)
//
#include <hip/hip_runtime.h>
#include <cfloat>
#include <climits>
#include <cstdint>
#include <cstddef>

#define ZD    128
#define NQ    256      // 4*64 queries
#define NB    4
#define NT    64
#define KK    100
#define CAP   2048
#define NSAMP 4096
#define RANK  24

// ---------------------------------------------------------------- k0: norms + zero counters
__global__ __launch_bounds__(256) void k0_norms(
    const float* __restrict__ Q, const float* __restrict__ T, int M,
    float* __restrict__ qn, float* __restrict__ tn, int* __restrict__ cnt) {
  int gid = blockIdx.x * 256 + threadIdx.x;
  if (gid < M) {
    const float* r = T + (size_t)gid * ZD;
    float s = 0.f;
    #pragma unroll
    for (int z4 = 0; z4 < 32; ++z4) {
      float4 v = *(const float4*)&r[z4 * 4];
      s = fmaf(v.x, v.x, s); s = fmaf(v.y, v.y, s);
      s = fmaf(v.z, v.z, s); s = fmaf(v.w, v.w, s);
    }
    tn[gid] = s;
  } else if (gid < M + NQ) {
    int q = gid - M;
    const float* r = Q + (size_t)q * ZD;
    float s = 0.f;
    #pragma unroll
    for (int z4 = 0; z4 < 32; ++z4) {
      float4 v = *(const float4*)&r[z4 * 4];
      s = fmaf(v.x, v.x, s); s = fmaf(v.y, v.y, s);
      s = fmaf(v.z, v.z, s); s = fmaf(v.w, v.w, s);
    }
    qn[q] = s;
  } else if (gid < M + 2 * NQ) {
    cnt[gid - M - NQ] = 0;
  }
}

// ---------------------------------------------------------------- k1: per-query threshold from sample
__global__ __launch_bounds__(256) void k1_thresh(
    const float* __restrict__ Q, const float* __restrict__ T, int M,
    const float* __restrict__ qn, const float* __restrict__ tn,
    float* __restrict__ thr) {
  __shared__ float qv[ZD];
  __shared__ float sd[NSAMP];
  __shared__ float red[256];
  __shared__ int   hist[256];
  const int q = blockIdx.x, tid = threadIdx.x;
  for (int z = tid; z < ZD; z += 256) qv[z] = Q[(size_t)q * ZD + z];
  __syncthreads();
  const float qnv = qn[q];
  for (int s = tid; s < NSAMP; s += 256) {
    const float* r = T + (size_t)s * ZD;
    float dot = 0.f;
    #pragma unroll 8
    for (int z = 0; z < ZD; ++z) dot = fmaf(qv[z], r[z], dot);
    sd[s] = fmaf(-2.0f, dot, qnv + tn[s]);
  }
  __syncthreads();
  float lm = FLT_MAX;
  for (int s = tid; s < NSAMP; s += 256) lm = fminf(lm, sd[s]);
  red[tid] = lm;
  __syncthreads();
  for (int o = 128; o > 0; o >>= 1) {
    if (tid < o) red[tid] = fminf(red[tid], red[tid + o]);
    __syncthreads();
  }
  const float dmin = red[0];
  hist[tid] = 0;
  __syncthreads();
  for (int s = tid; s < NSAMP; s += 256) {
    int b = (int)((sd[s] - dmin) * 3.2f);     // bin width 0.3125 over [dmin, dmin+80]
    b = b < 0 ? 0 : (b > 255 ? 255 : b);
    atomicAdd(&hist[b], 1);
  }
  __syncthreads();
  if (tid == 0) {
    int cum = 0; float Tq = dmin + 80.0f;
    for (int b = 0; b < 256; ++b) {
      cum += hist[b];
      if (cum >= RANK) { Tq = dmin + (float)(b + 1) * 0.3125f; break; }
    }
    thr[q] = Tq;
  }
}

// ---------------------------------------------------------------- k2: full distance pass, collect candidates
__global__ __launch_bounds__(256) void k2_collect(
    const float* __restrict__ Q, const float* __restrict__ T, int M,
    const float* __restrict__ qn, const float* __restrict__ tn,
    const float* __restrict__ thr, int* __restrict__ cnt,
    float* __restrict__ cand_d, int* __restrict__ cand_i) {
  __shared__ float Qs[ZD * 64];   // z-major [z][q]
  __shared__ float Ts[ZD * 64];   // z-major [z][t]
  const int tid = threadIdx.x;
  const int m0 = blockIdx.x * 64;
  const int qbase = blockIdx.y * 64;
  #pragma unroll
  for (int it = 0; it < 8; ++it) {
    int li = tid + it * 256;            // 0..2047
    int col = li & 63, z4 = li >> 6;    // z4: 0..31
    float4 v = *(const float4*)&Q[(size_t)(qbase + col) * ZD + z4 * 4];
    Qs[(z4 * 4 + 0) * 64 + col] = v.x;
    Qs[(z4 * 4 + 1) * 64 + col] = v.y;
    Qs[(z4 * 4 + 2) * 64 + col] = v.z;
    Qs[(z4 * 4 + 3) * 64 + col] = v.w;
    int m = m0 + col;
    float4 w = make_float4(0.f, 0.f, 0.f, 0.f);
    if (m < M) w = *(const float4*)&T[(size_t)m * ZD + z4 * 4];
    Ts[(z4 * 4 + 0) * 64 + col] = w.x;
    Ts[(z4 * 4 + 1) * 64 + col] = w.y;
    Ts[(z4 * 4 + 2) * 64 + col] = w.z;
    Ts[(z4 * 4 + 3) * 64 + col] = w.w;
  }
  __syncthreads();
  const int lq = (tid & 15) << 2;
  const int lt = (tid >> 4) << 2;
  float acc[16];
  #pragma unroll
  for (int x = 0; x < 16; ++x) acc[x] = 0.f;
  #pragma unroll 4
  for (int z = 0; z < ZD; ++z) {
    float4 a  = *(const float4*)&Qs[z * 64 + lq];
    float4 bb = *(const float4*)&Ts[z * 64 + lt];
    acc[0]  = fmaf(a.x, bb.x, acc[0]);  acc[1]  = fmaf(a.x, bb.y, acc[1]);
    acc[2]  = fmaf(a.x, bb.z, acc[2]);  acc[3]  = fmaf(a.x, bb.w, acc[3]);
    acc[4]  = fmaf(a.y, bb.x, acc[4]);  acc[5]  = fmaf(a.y, bb.y, acc[5]);
    acc[6]  = fmaf(a.y, bb.z, acc[6]);  acc[7]  = fmaf(a.y, bb.w, acc[7]);
    acc[8]  = fmaf(a.z, bb.x, acc[8]);  acc[9]  = fmaf(a.z, bb.y, acc[9]);
    acc[10] = fmaf(a.z, bb.z, acc[10]); acc[11] = fmaf(a.z, bb.w, acc[11]);
    acc[12] = fmaf(a.w, bb.x, acc[12]); acc[13] = fmaf(a.w, bb.y, acc[13]);
    acc[14] = fmaf(a.w, bb.z, acc[14]); acc[15] = fmaf(a.w, bb.w, acc[15]);
  }
  #pragma unroll
  for (int iq = 0; iq < 4; ++iq) {
    const int q = qbase + lq + iq;
    const float base = qn[q];
    const float Tq = thr[q];
    #pragma unroll
    for (int jt = 0; jt < 4; ++jt) {
      const int m = m0 + lt + jt;
      if (m < M) {
        float d = fmaf(-2.0f, acc[iq * 4 + jt], base + tn[m]);
        if (d < Tq) {
          int pos = atomicAdd(&cnt[q], 1);
          if (pos < CAP) {
            cand_d[(size_t)q * CAP + pos] = d;
            cand_i[(size_t)q * CAP + pos] = m;
          }
        }
      }
    }
  }
}

// ---------------------------------------------------------------- k3: exact top-K + softmax emissions
__global__ __launch_bounds__(256) void k3_select(
    const float* __restrict__ Q, const float* __restrict__ T, int M,
    const float* __restrict__ qn, const float* __restrict__ tn,
    const int* __restrict__ cnt, const float* __restrict__ cand_d,
    const int* __restrict__ cand_i, int* __restrict__ topi,
    float* __restrict__ emit) {
  __shared__ float sd[CAP];
  __shared__ int   si[CAP];
  __shared__ float qv[ZD];
  __shared__ float cd[256];
  __shared__ float ebuf[KK];
  __shared__ float ssum;
  const int q = blockIdx.x, tid = threadIdx.x;
  const int raw = cnt[q];
  const bool valid = (raw >= KK && raw <= CAP);
  if (valid) {
    for (int i = tid; i < CAP; i += 256) {
      if (i < raw) { sd[i] = cand_d[(size_t)q * CAP + i]; si[i] = cand_i[(size_t)q * CAP + i]; }
      else         { sd[i] = FLT_MAX; si[i] = INT_MAX; }
    }
    __syncthreads();
  } else {
    // brute-force exact fallback (essentially never taken; correctness net)
    for (int z = tid; z < ZD; z += 256) qv[z] = Q[(size_t)q * ZD + z];
    if (tid == 0) for (int k = 0; k < KK; ++k) { sd[k] = FLT_MAX; si[k] = INT_MAX; }
    __syncthreads();
    const float qnv = qn[q];
    for (int base = 0; base < M; base += 256) {
      int m = base + tid; float d = FLT_MAX;
      if (m < M) {
        const float* r = T + (size_t)m * ZD;
        float dot = 0.f;
        for (int z = 0; z < ZD; ++z) dot = fmaf(qv[z], r[z], dot);
        d = fmaf(-2.0f, dot, qnv + tn[m]);
      }
      cd[tid] = d;
      __syncthreads();
      if (tid == 0) {
        for (int e = 0; e < 256; ++e) {
          float dd = cd[e]; int mm = base + e;
          if (dd < sd[KK - 1] || (dd == sd[KK - 1] && mm < si[KK - 1])) {
            int pos = KK - 1;
            while (pos > 0 && (sd[pos - 1] > dd || (sd[pos - 1] == dd && si[pos - 1] > mm))) {
              sd[pos] = sd[pos - 1]; si[pos] = si[pos - 1]; --pos;
            }
            sd[pos] = dd; si[pos] = mm;
          }
        }
      }
      __syncthreads();
    }
    for (int i = KK + tid; i < CAP; i += 256) { sd[i] = FLT_MAX; si[i] = INT_MAX; }
    __syncthreads();
  }
  // bitonic sort ascending by (d, idx) — matches lax.top_k stable tie-break
  for (int k = 2; k <= CAP; k <<= 1) {
    for (int j = k >> 1; j > 0; j >>= 1) {
      for (int t = tid; t < CAP; t += 256) {
        int x = t ^ j;
        if (x > t) {
          bool asc = ((t & k) == 0);
          float d1 = sd[t], d2 = sd[x];
          int   i1 = si[t], i2 = si[x];
          bool g = (d1 > d2) || (d1 == d2 && i1 > i2);
          if (g == asc) { sd[t] = d2; sd[x] = d1; si[t] = i2; si[x] = i1; }
        }
      }
      __syncthreads();
    }
  }
  if (tid == 0) {
    float d0 = sd[0], sum = 0.f;
    for (int k = 0; k < KK; ++k) {
      float e = expf(d0 - sd[k]);   // softmax(-d): exp(-d_k - max(-d)) = exp(d0 - d_k)
      ebuf[k] = e; sum += e;
    }
    ssum = sum;
  }
  __syncthreads();
  if (tid < KK) {
    emit[(size_t)q * KK + tid] = ebuf[tid] / ssum;
    topi[(size_t)q * KK + tid] = si[tid];
  }
}

// ---------------------------------------------------------------- k4: transition matrices exp(-d)
__global__ __launch_bounds__(256) void k4_trans(
    const float* __restrict__ T, const int* __restrict__ topi,
    float* __restrict__ trans) {
  const int bt = blockIdx.x;                 // 0..251
  const int b = bt / (NT - 1), t = bt % (NT - 1);
  const int* iA = topi + (size_t)(b * NT + t) * KK;
  const int* iB = topi + (size_t)(b * NT + t + 1) * KK;
  __shared__ float As[KK * 132];             // stride 132: 16B-aligned rows, bank-rotating
  __shared__ float Bs[20 * 132];
  __shared__ float an[KK];
  __shared__ float bn[20];
  const int tid = threadIdx.x;
  for (int li = tid; li < KK * 32; li += 256) {
    int row = li >> 5, z4 = li & 31;
    float4 v = *(const float4*)&T[(size_t)iA[row] * ZD + z4 * 4];
    *(float4*)&As[row * 132 + z4 * 4] = v;
  }
  __syncthreads();
  if (tid < KK) {
    float s = 0.f;
    for (int z = 0; z < ZD; ++z) s = fmaf(As[tid * 132 + z], As[tid * 132 + z], s);
    an[tid] = s;
  }
  for (int c = 0; c < 5; ++c) {
    __syncthreads();  // protect Bs from previous chunk's readers (and publish an on c==0)
    for (int li = tid; li < 20 * 32; li += 256) {
      int row = li >> 5, z4 = li & 31;
      float4 v = *(const float4*)&T[(size_t)iB[c * 20 + row] * ZD + z4 * 4];
      *(float4*)&Bs[row * 132 + z4 * 4] = v;
    }
    __syncthreads();
    if (tid < 20) {
      float s = 0.f;
      for (int z = 0; z < ZD; ++z) s = fmaf(Bs[tid * 132 + z], Bs[tid * 132 + z], s);
      bn[tid] = s;
    }
    __syncthreads();
    if (tid < 125) {
      const int i0 = (tid / 5) * 4, j0 = (tid % 5) * 4;
      float acc[16];
      #pragma unroll
      for (int x = 0; x < 16; ++x) acc[x] = 0.f;
      for (int z4 = 0; z4 < 32; ++z4) {
        float4 a[4], bb[4];
        #pragma unroll
        for (int r = 0; r < 4; ++r) a[r] = *(const float4*)&As[(i0 + r) * 132 + z4 * 4];
        #pragma unroll
        for (int s = 0; s < 4; ++s) bb[s] = *(const float4*)&Bs[(j0 + s) * 132 + z4 * 4];
        #pragma unroll
        for (int r = 0; r < 4; ++r) {
          #pragma unroll
          for (int s = 0; s < 4; ++s) {
            acc[r * 4 + s] = fmaf(a[r].x, bb[s].x, acc[r * 4 + s]);
            acc[r * 4 + s] = fmaf(a[r].y, bb[s].y, acc[r * 4 + s]);
            acc[r * 4 + s] = fmaf(a[r].z, bb[s].z, acc[r * 4 + s]);
            acc[r * 4 + s] = fmaf(a[r].w, bb[s].w, acc[r * 4 + s]);
          }
        }
      }
      float* trow = trans + (size_t)bt * KK * KK;
      #pragma unroll
      for (int r = 0; r < 4; ++r)
        for (int s = 0; s < 4; ++s) {
          float d = fmaf(-2.0f, acc[r * 4 + s], an[i0 + r] + bn[j0 + s]);
          trow[(i0 + r) * KK + c * 20 + j0 + s] = expf(-d);
        }
    }
  }
}

// ---------------------------------------------------------------- k5: Viterbi + backtrack + gather
__global__ __launch_bounds__(256) void k5_viterbi(
    const float* __restrict__ T, const int* __restrict__ topi,
    const float* __restrict__ emit, const float* __restrict__ trans,
    int* __restrict__ backp, float* __restrict__ out) {
  const int b = blockIdx.x, tid = threadIdx.x;
  __shared__ float trS[KK * KK];
  __shared__ float v[KK], vn[KK];
  __shared__ int   path[NT];
  __shared__ float maxsh;
  __shared__ int   zflag;
  if (tid < KK) v[tid] = emit[(size_t)(b * NT) * KK + tid];
  if (tid == 0) zflag = 0;
  __syncthreads();
  for (int t = 1; t < NT; ++t) {
    const int zf = zflag;     // uniform: written only between barriers of prior iterations
    if (zf == 0) {
      const float* trg = trans + (size_t)(b * (NT - 1) + (t - 1)) * KK * KK;
      for (int li = tid; li < (KK * KK) / 4; li += 256)
        *(float4*)&trS[li * 4] = *(const float4*)&trg[li * 4];
      __syncthreads();
      if (tid < KK) {
        float best = -FLT_MAX; int bi = 0;
        for (int i = 0; i < KK; ++i) {
          float s = v[i] * trS[i * KK + tid];
          if (s > best) { best = s; bi = i; }   // strict > == argmax-first
        }
        vn[tid] = best * emit[(size_t)(b * NT + t) * KK + tid];
        backp[(size_t)(b * (NT - 1) + (t - 1)) * KK + tid] = bi;
      }
      __syncthreads();
      if (tid == 0) {
        float m = vn[0];
        for (int j = 1; j < KK; ++j) m = fmaxf(m, vn[j]);
        maxsh = m;
        if (m == 0.0f) zflag = 1;   // exact shortcut: all-zero v is absorbing
      }
      __syncthreads();
      if (tid < KK) v[tid] = vn[tid] / fmaxf(maxsh, 1e-30f);
    } else {
      // v == 0 everywhere: scores all 0 -> argmax = 0, v stays 0 (bit-exact vs dense)
      if (tid < KK) backp[(size_t)(b * (NT - 1) + (t - 1)) * KK + tid] = 0;
    }
    __syncthreads();
  }
  if (tid == 0) {
    float best = -FLT_MAX; int last = 0;
    for (int j = 0; j < KK; ++j) if (v[j] > best) { best = v[j]; last = j; }
    path[NT - 1] = last;
    for (int tt = NT - 2; tt >= 0; --tt)
      path[tt] = backp[(size_t)(b * (NT - 1) + tt) * KK + path[tt + 1]];
  }
  __syncthreads();
  for (int li = tid; li < NT * ZD; li += 256) {
    int t = li >> 7, z = li & 127;
    out[(size_t)(b * NT + t) * ZD + z] =
        T[(size_t)topi[(size_t)(b * NT + t) * KK + path[t]] * ZD + z];
  }
}

// ---------------------------------------------------------------- host
extern "C" void kernel_launch(void* const* d_in, const int* in_sizes, int n_in,
                              void* d_out, int out_size, void* d_ws, size_t ws_size,
                              hipStream_t stream) {
  const float* Q = (const float*)d_in[0];     // (4,64,128) fp32
  const float* T = (const float*)d_in[1];     // (100000,128) fp32
  float* out = (float*)d_out;                 // (4,64,128) fp32
  const int M = in_sizes[1] / ZD;

  char* p = (char*)d_ws;
  auto alloc = [&](size_t bytes) -> char* {
    char* r = p; p += (bytes + 511) & ~(size_t)511; return r;
  };
  float* qn     = (float*)alloc((size_t)NQ * 4);
  float* tn     = (float*)alloc((size_t)M * 4);
  float* thr    = (float*)alloc((size_t)NQ * 4);
  int*   cnt    = (int*)  alloc((size_t)NQ * 4);
  float* cand_d = (float*)alloc((size_t)NQ * CAP * 4);
  int*   cand_i = (int*)  alloc((size_t)NQ * CAP * 4);
  int*   topi   = (int*)  alloc((size_t)NQ * KK * 4);
  float* emit   = (float*)alloc((size_t)NQ * KK * 4);
  float* trans  = (float*)alloc((size_t)NB * (NT - 1) * KK * KK * 4);
  int*   backp  = (int*)  alloc((size_t)NB * (NT - 1) * KK * 4);

  const int g0 = (M + 2 * NQ + 255) / 256;
  k0_norms<<<g0, 256, 0, stream>>>(Q, T, M, qn, tn, cnt);
  k1_thresh<<<NQ, 256, 0, stream>>>(Q, T, M, qn, tn, thr);
  dim3 g2((M + 63) / 64, NQ / 64);
  k2_collect<<<g2, 256, 0, stream>>>(Q, T, M, qn, tn, thr, cnt, cand_d, cand_i);
  k3_select<<<NQ, 256, 0, stream>>>(Q, T, M, qn, tn, cnt, cand_d, cand_i, topi, emit);
  k4_trans<<<NB * (NT - 1), 256, 0, stream>>>(T, topi, trans);
  k5_viterbi<<<NB, 256, 0, stream>>>(T, topi, emit, trans, backp, out);
}